// Round 12
// baseline (47.990 us; speedup 1.0000x reference)
//
#include <hip/hip_runtime.h>
#include <math.h>

#define BB 4
#define CC 64
#define NN 4096
#define IND 8
#define HF 32
#define QBLK 32
#define THREADS 512
#define WAVES 8
#define MBLK 32
#define MCHUNK (NN/WAVES)    // 512 m's per wave
#define NBLK (MCHUNK/MBLK)   // 16 blocks

typedef __attribute__((ext_vector_type(8))) short bf16x8;
typedef __attribute__((ext_vector_type(4))) float f32x4;

static __device__ __forceinline__ unsigned short f2bf(float x) {
    unsigned int u = __float_as_uint(x);
    u = (u + 0x7FFFu + ((u >> 16) & 1u)) >> 16;   // RNE
    return (unsigned short)u;
}
static __device__ __forceinline__ float bf2f(unsigned short h) {
    return __uint_as_float(((unsigned int)h) << 16);
}
static __device__ __forceinline__ unsigned int pk2(float lo, float hi) {
    return (unsigned int)f2bf(lo) | ((unsigned int)f2bf(hi) << 16);
}
static __device__ __forceinline__ float ex2(float x) {
    return __builtin_amdgcn_exp2f(x);   // v_exp_f32 (2^x)
}

// m -> k-slot coding shared by P (in-register) and V (pre-permuted columns):
// k(m5) = (m5&3) | ((m5>>4)&1)<<2 | ((m5>>2)&3)<<3   (bijective on 0..31)

// Kernel 1: 1x1-conv projections -> packed bf16 workspaces.
// R12: in-wave c-split. 768 WGs x 256 threads (4 waves); og = bx>>7 selects
// role {0:f, 1:g, 2..5: V rows}. Each wave covers 32 positions twice:
// lanes 0-31 accumulate c in [0,32), lanes 32-63 c in [32,64) for the SAME
// positions; one __shfl_xor(32) per output combines. Chain 64->32 loads,
// occupancy 1.5->3 waves/SIMD, zero LDS/atomic/barrier combine.
__global__ __launch_bounds__(256) void proj_kernel(
    const float* __restrict__ x,
    const float* __restrict__ Wf, const float* __restrict__ bf,
    const float* __restrict__ Wg, const float* __restrict__ bg,
    const float* __restrict__ Wh, const float* __restrict__ bh,
    unsigned short* __restrict__ fpk,
    unsigned short* __restrict__ gpk,
    unsigned short* __restrict__ vpkT)
{
    __shared__ float swT[CC][8];       // [c][o], 2 KB

    int tid  = threadIdx.x;
    int bx   = blockIdx.x;
    int og   = bx >> 7;                // 0..5 (block-uniform)
    int rr   = bx & 127;
    int wave = tid >> 6;
    int lane = tid & 63;
    int pl    = lane & 31;             // position slot within wave
    int chalf = lane >> 5;             // 0: c 0..31, 1: c 32..63

    int p = rr * 128 + wave * 32 + pl; // 0..16383
    int b = p >> 12;
    int n = p & (NN - 1);
    const float* xp = x + (size_t)b * CC * NN + n;

    const float* W;
    const float* bias;
    if (og == 0)      { W = Wf; bias = bf; }
    else if (og == 1) { W = Wg; bias = bg; }
    else              { W = Wh + (og - 2) * 8 * CC; bias = bh + (og - 2) * 8; }

    // stage W -> LDS transposed (threads 0..127, coalesced float4)
    if (tid < 128) {
        float4 wv = *(const float4*)(W + tid * 4);
        int o  = (tid * 4) >> 6;
        int c0 = (tid * 4) & 63;
        swT[c0 + 0][o] = wv.x;
        swT[c0 + 1][o] = wv.y;
        swT[c0 + 2][o] = wv.z;
        swT[c0 + 3][o] = wv.w;
    }

    // issue this lane-half's 32 coalesced loads; pin live before FMAs
    float xv[32];
    #pragma unroll
    for (int cc = 0; cc < 32; cc++)
        xv[cc] = xp[(size_t)(chalf * 32 + cc) * NN];
    #pragma unroll
    for (int cc = 0; cc < 32; cc++) asm volatile("" : "+v"(xv[cc]));

    __syncthreads();

    float a[8];
    #pragma unroll
    for (int o = 0; o < 8; o++) a[o] = (chalf == 0) ? bias[o] : 0.f;
    #pragma unroll
    for (int cc = 0; cc < 32; cc++) {
        int c = chalf * 32 + cc;            // uniform per half-wave
        float4 w0 = *(const float4*)&swT[c][0];
        float4 w1 = *(const float4*)&swT[c][4];
        float v = xv[cc];
        a[0] += w0.x * v; a[1] += w0.y * v; a[2] += w0.z * v; a[3] += w0.w * v;
        a[4] += w1.x * v; a[5] += w1.y * v; a[6] += w1.z * v; a[7] += w1.w * v;
    }
    // combine halves in-wave; both halves end with the full sum
    #pragma unroll
    for (int o = 0; o < 8; o++) a[o] += __shfl_xor(a[o], 32);

    const float LOG2E = 1.4426950408889634f;
    size_t base = (size_t)b * NN + n;

    if (og == 0) {
        union { unsigned short s[16]; uint4 q[2]; } fo;
        #pragma unroll
        for (int o = 0; o < 8; o++) {
            unsigned short hi = f2bf(a[o]);
            unsigned short lo = f2bf(a[o] - bf2f(hi));
            fo.s[o] = hi; fo.s[8 + o] = lo;
        }
        // lane-half splits the 32-B store
        *(uint4*)(fpk + base * 16 + chalf * 8) = fo.q[chalf];
    } else if (og == 1) {
        union { unsigned short s[32]; uint4 q[4]; } go;
        #pragma unroll
        for (int o = 0; o < 8; o++) {
            float gsc = a[o] * LOG2E;              // exp -> exp2 fold
            unsigned short hi = f2bf(gsc);
            unsigned short lo = f2bf(gsc - bf2f(hi));
            go.s[o] = hi; go.s[8 + o] = hi; go.s[16 + o] = lo; go.s[24 + o] = lo;
        }
        *(uint4*)(gpk + base * 32 + chalf * 16 + 0) = go.q[chalf * 2 + 0];
        *(uint4*)(gpk + base * 32 + chalf * 16 + 8) = go.q[chalf * 2 + 1];
    } else {
        int m5 = n & 31;
        int code = (m5 & 3) | (((m5 >> 4) & 1) << 2) | (((m5 >> 2) & 3) << 3);
        int pos = (n & ~31) | code;
        unsigned short* vp = vpkT + (size_t)b * HF * NN + pos;
        int h0 = (og - 2) * 8 + chalf * 4;         // half writes 4 rows
        #pragma unroll
        for (int o = 0; o < 4; o++)
            vp[(size_t)(h0 + o) * NN] = f2bf(a[chalf * 4 + o]);
    }
}

// Kernel 2: register-only MFMA flash attention + fused Wv/gamma/residual.
// (unchanged from R10/R11 -- isolate proj's delta this round)
// QBLK=32: 512 WGs -> 2 WG/CU = 4 waves/SIMD; live set ~90 VGPR bounded by
// __launch_bounds__(512,4); XCD-swizzled blockIdx; deterministic combine.
__global__ __launch_bounds__(THREADS, 4) void attn_kernel(
    const unsigned short* __restrict__ fpk,
    const unsigned short* __restrict__ gpk,
    const unsigned short* __restrict__ vpkT,
    const float* __restrict__ Wv, const float* __restrict__ bv,
    const float* __restrict__ gamma,
    const float* __restrict__ x, float* __restrict__ out)
{
    __shared__ float sl[WAVES][QBLK][HF + 1];   // 8*32*33*4 = 33.8 KB

    int tid  = threadIdx.x;
    int wave = tid >> 6;
    int lane = tid & 63;
    int c15  = lane & 15;
    int g4   = lane >> 4;

    // bijective XCD swizzle: 512 blocks = 8 XCD x 64 contiguous logical ids
    int l  = (blockIdx.x & 7) * 64 + (blockIdx.x >> 3);
    int b  = l >> 7;                  // 128 q-tiles per batch
    int n0 = (l & 127) * QBLK;

    // Q as B-operand: col=c15 -> q = n0+qg*16+c15, k-octet g4 -> [fh,fl,fh,fl]
    bf16x8 bq[2];
    #pragma unroll
    for (int qg = 0; qg < 2; qg++)
        bq[qg] = *(const bf16x8*)(fpk
                  + ((size_t)(b * NN + n0 + qg*16 + c15)) * 16 + (g4 & 1) * 8);

    f32x4 zero4 = {0.f, 0.f, 0.f, 0.f};
    f32x4 acc[2][2];
    float Lacc[2] = {0.f, 0.f};
    #pragma unroll
    for (int qg = 0; qg < 2; qg++) { acc[qg][0] = zero4; acc[qg][1] = zero4; }

    const unsigned short* gsrc = gpk  + (size_t)b * NN * 32;
    const unsigned short* vsrc = vpkT + (size_t)b * HF * NN;
    int mbase = wave * MCHUNK;

    // K A-fragment: row=c15 -> m = m0+mg*16+c15, octet g4
    // V B-fragment: col=c15 -> h = hg*16+c15, k-octet g4 -> cols m0+g4*8..+7
    bf16x8 akc[2], vbc[2];
    {
        int m0 = mbase;
        akc[0] = *(const bf16x8*)(gsrc + (size_t)(m0 + c15)      * 32 + g4*8);
        akc[1] = *(const bf16x8*)(gsrc + (size_t)(m0 + 16 + c15) * 32 + g4*8);
        vbc[0] = *(const bf16x8*)(vsrc + (size_t)(c15)      * NN + m0 + g4*8);
        vbc[1] = *(const bf16x8*)(vsrc + (size_t)(16 + c15) * NN + m0 + g4*8);
    }

    #pragma unroll 2
    for (int t = 0; t < NBLK; t++) {
        bf16x8 akn[2], vbn[2];
        if (t + 1 < NBLK) {
            int m1 = mbase + (t + 1) * MBLK;
            akn[0] = *(const bf16x8*)(gsrc + (size_t)(m1 + c15)      * 32 + g4*8);
            akn[1] = *(const bf16x8*)(gsrc + (size_t)(m1 + 16 + c15) * 32 + g4*8);
            vbn[0] = *(const bf16x8*)(vsrc + (size_t)(c15)      * NN + m1 + g4*8);
            vbn[1] = *(const bf16x8*)(vsrc + (size_t)(16 + c15) * NN + m1 + g4*8);
        }

        // swapped QK^T: D[m-row][q-col]; exact hi/lo product
        f32x4 sf[2][2];
        #pragma unroll
        for (int mg = 0; mg < 2; mg++)
            #pragma unroll
            for (int qg = 0; qg < 2; qg++)
                sf[qg][mg] = __builtin_amdgcn_mfma_f32_16x16x32_bf16(
                    akc[mg], bq[qg], zero4, 0, 0, 0);

        // exp2 (log2e pre-folded; no max shift: |S'| < ~25, f32-safe),
        // pack straight into the PV A-fragment (k = r + 4*mg + 8*g4)
        bf16x8 pa[2];
        #pragma unroll
        for (int qg = 0; qg < 2; qg++) {
            float e00 = ex2(sf[qg][0][0]), e01 = ex2(sf[qg][0][1]);
            float e02 = ex2(sf[qg][0][2]), e03 = ex2(sf[qg][0][3]);
            float e10 = ex2(sf[qg][1][0]), e11 = ex2(sf[qg][1][1]);
            float e12 = ex2(sf[qg][1][2]), e13 = ex2(sf[qg][1][3]);
            Lacc[qg] += ((e00 + e01) + (e02 + e03)) + ((e10 + e11) + (e12 + e13));
            union { unsigned int u[4]; bf16x8 v; } pp;
            pp.u[0] = pk2(e00, e01); pp.u[1] = pk2(e02, e03);
            pp.u[2] = pk2(e10, e11); pp.u[3] = pk2(e12, e13);
            pa[qg] = pp.v;
        }

        // P * V: acc[qg][hg], D: col=c15=h, row=g4*4+r=q
        #pragma unroll
        for (int qg = 0; qg < 2; qg++)
            #pragma unroll
            for (int hg = 0; hg < 2; hg++)
                acc[qg][hg] = __builtin_amdgcn_mfma_f32_16x16x32_bf16(
                    pa[qg], vbc[hg], acc[qg][hg], 0, 0, 0);

        if (t + 1 < NBLK) {
            akc[0] = akn[0]; akc[1] = akn[1];
            vbc[0] = vbn[0]; vbc[1] = vbn[1];
        }
    }

    // ---- deterministic wave combine (no atomics) ----
    #pragma unroll
    for (int qg = 0; qg < 2; qg++)
        #pragma unroll
        for (int hg = 0; hg < 2; hg++)
            #pragma unroll
            for (int r = 0; r < 4; r++)
                sl[wave][qg*16 + g4*4 + r][hg*16 + c15] = acc[qg][hg][r];
    #pragma unroll
    for (int qg = 0; qg < 2; qg++) {
        float t = Lacc[qg];
        t += __shfl_xor(t, 16);
        t += __shfl_xor(t, 32);
        if (g4 == 0) sl[wave][qg*16 + c15][HF] = t;
    }
    __syncthreads();

    // sum the 8 wave slices into slice 0: 512 threads over 32 q x 33 cols
    {
        int q = tid & 31;
        for (int col = tid >> 5; col < HF + 1; col += 16) {
            float s = sl[0][q][col];
            #pragma unroll
            for (int w2 = 1; w2 < WAVES; w2++) s += sl[w2][q][col];
            sl[0][q][col] = s;
        }
    }
    __syncthreads();

    // epilogue: normalize, Wv projection, gamma, residual
    // 512 threads = 32 q x 16 channel-blocks of 4
    int q  = tid & 31;
    int cb = tid >> 5;
    float rL = 1.f / sl[0][q][HF];
    float o_[HF];
    #pragma unroll
    for (int h = 0; h < HF; h++) o_[h] = sl[0][q][h] * rL;
    float gm = gamma[0];
    size_t obase = (size_t)b * CC * NN + n0 + q;
    for (int c = cb*4; c < cb*4 + 4; c++) {
        float v = bv[c];
        #pragma unroll
        for (int h = 0; h < HF; h++) v += Wv[c*HF + h] * o_[h];
        size_t a = obase + (size_t)c * NN;
        out[a] = gm * v + x[a];
    }
}

extern "C" void kernel_launch(void* const* d_in, const int* in_sizes, int n_in,
                              void* d_out, int out_size, void* d_ws, size_t ws_size,
                              hipStream_t stream) {
    const float* x     = (const float*)d_in[0];
    const float* Wf    = (const float*)d_in[1];
    const float* bf    = (const float*)d_in[2];
    const float* Wg    = (const float*)d_in[3];
    const float* bg    = (const float*)d_in[4];
    const float* Wh    = (const float*)d_in[5];
    const float* bh    = (const float*)d_in[6];
    const float* Wv    = (const float*)d_in[7];
    const float* bv    = (const float*)d_in[8];
    const float* gamma = (const float*)d_in[9];
    float* out = (float*)d_out;

    unsigned short* ws   = (unsigned short*)d_ws;
    unsigned short* fpk  = ws;                               // B*N*16
    unsigned short* gpk  = ws + (size_t)BB*NN*16;            // B*N*32
    unsigned short* vpkT = ws + (size_t)BB*NN*48;            // B*32*N
    // total 2.62 MB

    proj_kernel<<<(BB*NN/128)*6, 256, 0, stream>>>(x, Wf, bf, Wg, bg, Wh, bh,
                                                   fpk, gpk, vpkT);
    attn_kernel<<<BB*(NN/QBLK), THREADS, 0, stream>>>(fpk, gpk, vpkT,
                                                      Wv, bv, gamma, x, out);
}

// Round 13
// 32.933 us; speedup vs baseline: 1.4572x; 1.4572x over previous
//
#include <hip/hip_runtime.h>
#include <math.h>

#define BB 4
#define CC 64
#define NN 4096
#define IND 8
#define HF 32
#define QBLK 32
#define THREADS 512
#define WAVES 8
#define MBLK 32
#define MCHUNK (NN/WAVES)    // 512 m's per wave
#define NBLK (MCHUNK/MBLK)   // 16 blocks

typedef __attribute__((ext_vector_type(8))) short bf16x8;
typedef __attribute__((ext_vector_type(4))) float f32x4;

static __device__ __forceinline__ unsigned short f2bf(float x) {
    unsigned int u = __float_as_uint(x);
    u = (u + 0x7FFFu + ((u >> 16) & 1u)) >> 16;   // RNE
    return (unsigned short)u;
}
static __device__ __forceinline__ float bf2f(unsigned short h) {
    return __uint_as_float(((unsigned int)h) << 16);
}
static __device__ __forceinline__ unsigned int pk2(float lo, float hi) {
    return (unsigned int)f2bf(lo) | ((unsigned int)f2bf(hi) << 16);
}
static __device__ __forceinline__ float ex2(float x) {
    return __builtin_amdgcn_exp2f(x);   // v_exp_f32 (2^x)
}

// m -> k-slot coding shared by P (in-register) and V (blocked layout):
// k(m5) = (m5&3) | ((m5>>4)&1)<<2 | ((m5>>2)&3)<<3   (bijective on 0..31)
//
// V layout (R13): vblk[b][mb][hg][c15][ks] u16, mb = m>>5 (128 per batch),
// hg = h>>4, c15 = h&15, ks = k(m&31). One (mb) block = 1024 u16 = 2 KB
// contiguous -> attn's B-fragment wave-load spans contiguous 2 KB (was 16
// segments at 8 KB stride = same-L2-channel serialization).

// Kernel 1: 1x1-conv projections -> packed bf16 workspaces. (R11 form)
// Output-role split: 768 WGs x 128 threads; og = bx>>7 selects role
// {0:f, 1:g, 2..5: V rows}. Role weights staged in LDS transposed; x loads
// all issued then pinned live (latency overlap); no LDS/atomic combine.
__global__ __launch_bounds__(128) void proj_kernel(
    const float* __restrict__ x,
    const float* __restrict__ Wf, const float* __restrict__ bf,
    const float* __restrict__ Wg, const float* __restrict__ bg,
    const float* __restrict__ Wh, const float* __restrict__ bh,
    unsigned short* __restrict__ fpk,
    unsigned short* __restrict__ gpk,
    unsigned short* __restrict__ vblk)
{
    __shared__ float swT[CC][8];       // [c][o], 2 KB

    int tid = threadIdx.x;
    int bx  = blockIdx.x;
    int og  = bx >> 7;                 // 0..5 (block-uniform -> scalar branches)
    int p   = (bx & 127) * 128 + tid;  // 0..16383
    int b = p >> 12;
    int n = p & (NN - 1);
    const float* xp = x + (size_t)b * CC * NN + n;

    const float* W;
    const float* bias;
    if (og == 0)      { W = Wf; bias = bf; }
    else if (og == 1) { W = Wg; bias = bg; }
    else              { W = Wh + (og - 2) * 8 * CC; bias = bh + (og - 2) * 8; }

    // stage W -> LDS transposed (one-time)
    {
        float4 wv = *(const float4*)(W + tid * 4);   // coalesced
        int o = (tid * 4) >> 6;
        int c0 = (tid * 4) & 63;
        swT[c0 + 0][o] = wv.x;
        swT[c0 + 1][o] = wv.y;
        swT[c0 + 2][o] = wv.z;
        swT[c0 + 3][o] = wv.w;
    }

    // issue all 64 coalesced loads, then pin them live before any FMA
    float xv[CC];
    #pragma unroll
    for (int c = 0; c < CC; c++) xv[c] = xp[(size_t)c * NN];
    #pragma unroll
    for (int c = 0; c < CC; c++) asm volatile("" : "+v"(xv[c]));

    __syncthreads();

    float a[8];
    #pragma unroll
    for (int o = 0; o < 8; o++) a[o] = bias[o];
    #pragma unroll
    for (int c = 0; c < CC; c++) {
        float4 w0 = *(const float4*)&swT[c][0];   // ds_read_b128, broadcast
        float4 w1 = *(const float4*)&swT[c][4];
        float v = xv[c];
        a[0] += w0.x * v; a[1] += w0.y * v; a[2] += w0.z * v; a[3] += w0.w * v;
        a[4] += w1.x * v; a[5] += w1.y * v; a[6] += w1.z * v; a[7] += w1.w * v;
    }

    const float LOG2E = 1.4426950408889634f;
    size_t base = (size_t)b * NN + n;

    if (og == 0) {
        union { unsigned short s[16]; uint4 q[2]; } fo;
        #pragma unroll
        for (int o = 0; o < 8; o++) {
            unsigned short hi = f2bf(a[o]);
            unsigned short lo = f2bf(a[o] - bf2f(hi));
            fo.s[o] = hi; fo.s[8 + o] = lo;
        }
        uint4* fdst = (uint4*)(fpk + base * 16);
        fdst[0] = fo.q[0]; fdst[1] = fo.q[1];
    } else if (og == 1) {
        union { unsigned short s[32]; uint4 q[4]; } go;
        #pragma unroll
        for (int o = 0; o < 8; o++) {
            float gsc = a[o] * LOG2E;              // exp -> exp2 fold
            unsigned short hi = f2bf(gsc);
            unsigned short lo = f2bf(gsc - bf2f(hi));
            go.s[o] = hi; go.s[8 + o] = hi; go.s[16 + o] = lo; go.s[24 + o] = lo;
        }
        uint4* gdst = (uint4*)(gpk + base * 32);
        #pragma unroll
        for (int k = 0; k < 4; k++) gdst[k] = go.q[k];
    } else {
        int m5 = n & 31;
        int code = (m5 & 3) | (((m5 >> 4) & 1) << 2) | (((m5 >> 2) & 3) << 3);
        int mb = (n >> 5);                          // m-block within batch
        int h0 = (og - 2) * 8;
        int hg = h0 >> 4;                           // block-uniform
        unsigned short* vp = vblk + (size_t)b * (NN/32) * 1024
                           + (size_t)mb * 1024 + hg * 512 + code;
        #pragma unroll
        for (int o = 0; o < 8; o++)
            vp[((h0 + o) & 15) * 32] = f2bf(a[o]);
    }
}

// Kernel 2: register-only MFMA flash attention + fused Wv/gamma/residual.
// (R10 form; only the V read addressing changed to the blocked layout)
// QBLK=32: 512 WGs -> 2 WG/CU = 4 waves/SIMD; live set ~90 VGPR bounded by
// __launch_bounds__(512,4); XCD-swizzled blockIdx; deterministic combine.
__global__ __launch_bounds__(THREADS, 4) void attn_kernel(
    const unsigned short* __restrict__ fpk,
    const unsigned short* __restrict__ gpk,
    const unsigned short* __restrict__ vblk,
    const float* __restrict__ Wv, const float* __restrict__ bv,
    const float* __restrict__ gamma,
    const float* __restrict__ x, float* __restrict__ out)
{
    __shared__ float sl[WAVES][QBLK][HF + 1];   // 8*32*33*4 = 33.8 KB

    int tid  = threadIdx.x;
    int wave = tid >> 6;
    int lane = tid & 63;
    int c15  = lane & 15;
    int g4   = lane >> 4;

    // bijective XCD swizzle: 512 blocks = 8 XCD x 64 contiguous logical ids
    int l  = (blockIdx.x & 7) * 64 + (blockIdx.x >> 3);
    int b  = l >> 7;                  // 128 q-tiles per batch
    int n0 = (l & 127) * QBLK;

    // Q as B-operand: col=c15 -> q = n0+qg*16+c15, k-octet g4 -> [fh,fl,fh,fl]
    bf16x8 bq[2];
    #pragma unroll
    for (int qg = 0; qg < 2; qg++)
        bq[qg] = *(const bf16x8*)(fpk
                  + ((size_t)(b * NN + n0 + qg*16 + c15)) * 16 + (g4 & 1) * 8);

    f32x4 zero4 = {0.f, 0.f, 0.f, 0.f};
    f32x4 acc[2][2];
    float Lacc[2] = {0.f, 0.f};
    #pragma unroll
    for (int qg = 0; qg < 2; qg++) { acc[qg][0] = zero4; acc[qg][1] = zero4; }

    const unsigned short* gsrc = gpk  + (size_t)b * NN * 32;
    const unsigned short* vsrc = vblk + (size_t)b * (NN/32) * 1024;
    int mbase = wave * MCHUNK;
    int mb0   = wave * NBLK;          // m-block index = wave*16 + t

    // K A-fragment: row=c15 -> m = m0+mg*16+c15, octet g4 (contiguous 2KB/blk)
    // V B-fragment: lane(c15,g4) -> vsrc + mb*1024 + hg*512 + c15*32 + g4*8
    bf16x8 akc[2], vbc[2];
    {
        int m0 = mbase;
        akc[0] = *(const bf16x8*)(gsrc + (size_t)(m0 + c15)      * 32 + g4*8);
        akc[1] = *(const bf16x8*)(gsrc + (size_t)(m0 + 16 + c15) * 32 + g4*8);
        const unsigned short* vb = vsrc + (size_t)mb0 * 1024 + c15*32 + g4*8;
        vbc[0] = *(const bf16x8*)(vb);
        vbc[1] = *(const bf16x8*)(vb + 512);
    }

    #pragma unroll 2
    for (int t = 0; t < NBLK; t++) {
        bf16x8 akn[2], vbn[2];
        if (t + 1 < NBLK) {
            int m1 = mbase + (t + 1) * MBLK;
            akn[0] = *(const bf16x8*)(gsrc + (size_t)(m1 + c15)      * 32 + g4*8);
            akn[1] = *(const bf16x8*)(gsrc + (size_t)(m1 + 16 + c15) * 32 + g4*8);
            const unsigned short* vb = vsrc + (size_t)(mb0 + t + 1) * 1024
                                     + c15*32 + g4*8;
            vbn[0] = *(const bf16x8*)(vb);
            vbn[1] = *(const bf16x8*)(vb + 512);
        }

        // swapped QK^T: D[m-row][q-col]; exact hi/lo product
        f32x4 sf[2][2];
        #pragma unroll
        for (int mg = 0; mg < 2; mg++)
            #pragma unroll
            for (int qg = 0; qg < 2; qg++)
                sf[qg][mg] = __builtin_amdgcn_mfma_f32_16x16x32_bf16(
                    akc[mg], bq[qg], zero4, 0, 0, 0);

        // exp2 (log2e pre-folded; no max shift: |S'| < ~25, f32-safe),
        // pack straight into the PV A-fragment (k = r + 4*mg + 8*g4)
        bf16x8 pa[2];
        #pragma unroll
        for (int qg = 0; qg < 2; qg++) {
            float e00 = ex2(sf[qg][0][0]), e01 = ex2(sf[qg][0][1]);
            float e02 = ex2(sf[qg][0][2]), e03 = ex2(sf[qg][0][3]);
            float e10 = ex2(sf[qg][1][0]), e11 = ex2(sf[qg][1][1]);
            float e12 = ex2(sf[qg][1][2]), e13 = ex2(sf[qg][1][3]);
            Lacc[qg] += ((e00 + e01) + (e02 + e03)) + ((e10 + e11) + (e12 + e13));
            union { unsigned int u[4]; bf16x8 v; } pp;
            pp.u[0] = pk2(e00, e01); pp.u[1] = pk2(e02, e03);
            pp.u[2] = pk2(e10, e11); pp.u[3] = pk2(e12, e13);
            pa[qg] = pp.v;
        }

        // P * V: acc[qg][hg], D: col=c15=h, row=g4*4+r=q
        #pragma unroll
        for (int qg = 0; qg < 2; qg++)
            #pragma unroll
            for (int hg = 0; hg < 2; hg++)
                acc[qg][hg] = __builtin_amdgcn_mfma_f32_16x16x32_bf16(
                    pa[qg], vbc[hg], acc[qg][hg], 0, 0, 0);

        if (t + 1 < NBLK) {
            akc[0] = akn[0]; akc[1] = akn[1];
            vbc[0] = vbn[0]; vbc[1] = vbn[1];
        }
    }

    // ---- deterministic wave combine (no atomics) ----
    #pragma unroll
    for (int qg = 0; qg < 2; qg++)
        #pragma unroll
        for (int hg = 0; hg < 2; hg++)
            #pragma unroll
            for (int r = 0; r < 4; r++)
                sl[wave][qg*16 + g4*4 + r][hg*16 + c15] = acc[qg][hg][r];
    #pragma unroll
    for (int qg = 0; qg < 2; qg++) {
        float t = Lacc[qg];
        t += __shfl_xor(t, 16);
        t += __shfl_xor(t, 32);
        if (g4 == 0) sl[wave][qg*16 + c15][HF] = t;
    }
    __syncthreads();

    // sum the 8 wave slices into slice 0: 512 threads over 32 q x 33 cols
    {
        int q = tid & 31;
        for (int col = tid >> 5; col < HF + 1; col += 16) {
            float s = sl[0][q][col];
            #pragma unroll
            for (int w2 = 1; w2 < WAVES; w2++) s += sl[w2][q][col];
            sl[0][q][col] = s;
        }
    }
    __syncthreads();

    // epilogue: normalize, Wv projection, gamma, residual
    // 512 threads = 32 q x 16 channel-blocks of 4
    int q  = tid & 31;
    int cb = tid >> 5;
    float rL = 1.f / sl[0][q][HF];
    float o_[HF];
    #pragma unroll
    for (int h = 0; h < HF; h++) o_[h] = sl[0][q][h] * rL;
    float gm = gamma[0];
    size_t obase = (size_t)b * CC * NN + n0 + q;
    for (int c = cb*4; c < cb*4 + 4; c++) {
        float v = bv[c];
        #pragma unroll
        for (int h = 0; h < HF; h++) v += Wv[c*HF + h] * o_[h];
        size_t a = obase + (size_t)c * NN;
        out[a] = gm * v + x[a];
    }
}

extern "C" void kernel_launch(void* const* d_in, const int* in_sizes, int n_in,
                              void* d_out, int out_size, void* d_ws, size_t ws_size,
                              hipStream_t stream) {
    const float* x     = (const float*)d_in[0];
    const float* Wf    = (const float*)d_in[1];
    const float* bf    = (const float*)d_in[2];
    const float* Wg    = (const float*)d_in[3];
    const float* bg    = (const float*)d_in[4];
    const float* Wh    = (const float*)d_in[5];
    const float* bh    = (const float*)d_in[6];
    const float* Wv    = (const float*)d_in[7];
    const float* bv    = (const float*)d_in[8];
    const float* gamma = (const float*)d_in[9];
    float* out = (float*)d_out;

    unsigned short* ws   = (unsigned short*)d_ws;
    unsigned short* fpk  = ws;                               // B*N*16
    unsigned short* gpk  = ws + (size_t)BB*NN*16;            // B*N*32
    unsigned short* vblk = ws + (size_t)BB*NN*48;            // B*(N/32)*1024
    // total 2.62 MB

    proj_kernel<<<(BB*NN/128)*6, 128, 0, stream>>>(x, Wf, bf, Wg, bg, Wh, bh,
                                                   fpk, gpk, vblk);
    attn_kernel<<<BB*(NN/QBLK), THREADS, 0, stream>>>(fpk, gpk, vblk,
                                                      Wv, bv, gamma, x, out);
}